// Round 7
// baseline (571.060 us; speedup 1.0000x reference)
//
#include <hip/hip_runtime.h>
#include <math.h>

// Problem constants
#define TT 32
#define BB 128
#define DD 256
#define HH 768
#define MAXP 8

// Decomposition: 8 rowgroups (16 rows) x 12 col-blocks (64 cols), 256 thr (4 waves = 4 col-tiles)
#define RG   8
#define RPG  16
#define CB   12
#define CS   64
#define NTH  256
#define NCH  24    // K chunks of 32

#define OFF_LAST  ((size_t)TT * BB * HH)
#define OFF_PCOST (OFF_LAST + (size_t)BB * HH)
#define OFF_STEPS (OFF_PCOST + BB)

#define ASCOPE __HIP_MEMORY_SCOPE_AGENT

typedef __attribute__((ext_vector_type(8))) short s16x8;
typedef __attribute__((ext_vector_type(4))) float f32x4;
typedef unsigned long long ull;

static __device__ __forceinline__ unsigned short f2bf(float f) {
    unsigned u = __float_as_uint(f);
    u = (u + 0x7fffu + ((u >> 16) & 1u)) >> 16;   // RNE
    return (unsigned short)u;
}
static __device__ __forceinline__ float bf2f(unsigned short h) {
    return __uint_as_float(((unsigned)h) << 16);
}
// bf16-target precision is 2^-9; __expf error ~1e-6 is invisible.
static __device__ __forceinline__ float fast_tanh(float v) {
    return 1.f - 2.f / (__expf(2.f * v) + 1.f);
}

union AU { f32x4 f; s16x8 s; unsigned short e[8]; ull u[2]; };

__launch_bounds__(NTH, 1)
__global__ void act_kernel(const float* __restrict__ x,
                           const float* __restrict__ Wih,
                           const float* __restrict__ Whh,
                           const float* __restrict__ bih,
                           const float* __restrict__ bhh,
                           const float* __restrict__ wpv,
                           const float* __restrict__ bp,
                           float* __restrict__ out,
                           unsigned* __restrict__ flags,
                           ull* __restrict__ hxe,
                           float* __restrict__ zpt)
{
    const int tid  = threadIdx.x;
    const int rg   = blockIdx.x & 7;     // rowgroup -> XCD (perf heuristic only)
    const int cbk  = blockIdx.x >> 3;    // col-block [0,12)
    const int r0   = rg * RPG;
    const int c0   = cbk * CS;
    const int CT   = tid >> 6;           // wave = col-tile [0,4)
    const int lane = tid & 63;
    const int am   = lane & 15;          // A-frag row / C-frag col
    const int aq   = lane >> 4;

    // LDS ~69 KB
    __shared__ s16x8 A_s[NCH * 64];        // current hx A-frags (finalize or exchange)
    __shared__ s16x8 WB_s[4 * 8 * 64];     // Wih B-frags (32 KB)
    __shared__ s16x8 xA_s[8 * 64];         // x_t A-frags (8 KB)
    __shared__ __align__(16) unsigned short hxn_s[RPG][72];   // new hx slice, bf16 (pad 72)
    __shared__ float zred_s[RPG][CB];      // staged z partials (row x producer)
    __shared__ float wp_s[CS];

    // ---- init: Whh B-frags -> permanent VGPRs (96) ----
    s16x8 Breg[NCH];
    {
        const float* wr = Whh + (size_t)(c0 + CT*16 + am) * HH + aq*8;
        for (int ch = 0; ch < NCH; ++ch) {
            float4 a0 = *(const float4*)(wr + ch*32);
            float4 a1 = *(const float4*)(wr + ch*32 + 4);
            union { s16x8 v; unsigned short e[8]; } u;
            u.e[0]=f2bf(a0.x); u.e[1]=f2bf(a0.y); u.e[2]=f2bf(a0.z); u.e[3]=f2bf(a0.w);
            u.e[4]=f2bf(a1.x); u.e[5]=f2bf(a1.y); u.e[6]=f2bf(a1.z); u.e[7]=f2bf(a1.w);
            Breg[ch] = u.v;
        }
    }
    // Wih B-frags -> LDS (row stride 257 unaligned: scalar loads, init-only)
    for (int ch = 0; ch < 8; ++ch) {
        const float* wr = Wih + (size_t)(c0 + CT*16 + am) * (DD+1) + ch*32 + aq*8;
        union { s16x8 v; unsigned short e[8]; } u;
        #pragma unroll
        for (int j = 0; j < 8; ++j) u.e[j] = f2bf(wr[j]);
        WB_s[(CT*8 + ch)*64 + lane] = u.v;
    }
    if (tid < CS) wp_s[tid] = wpv[c0 + tid];
    // per-lane column constants (col = c0 + CT*16 + am)
    const int myc = c0 + CT*16 + am;
    const float bs_lane = bih[myc] + bhh[myc];
    const float wfl     = Wih[(size_t)myc*(DD+1) + DD];   // ponder-flag column
    const float bp0     = bp[0];
    {
        s16x8 z8 = {0,0,0,0,0,0,0,0};
        #pragma unroll
        for (int j = 0; j < 6; ++j) A_s[j*NTH + tid] = z8;   // hx0 = 0
    }

    float pc = 0.f;     // per-lane pcost for row am
    unsigned it = 0;    // number of publishes completed by this block

    // Publish: wave 0 pushes hxn_s (A-frag layout) + 16 z-row partials via agent-scope
    // write-through atomic stores, waits for its OWN stores to reach the coherence
    // point (raw vmcnt(0) -- no cache-flushing fence), then sets the flag.
    auto publish = [&]() {
        const unsigned par = it & 1u;
        if (CT == 0) {
            ull*   exw = hxe + (size_t)(rg*2 + par) * (NCH*64*2);
            float* zpw = zpt + (size_t)(rg*2 + par) * (RPG*CB);
            const ull s00 = ((const ull*)&hxn_s[am][aq*8])[0];
            const ull s01 = ((const ull*)&hxn_s[am][aq*8])[1];
            const ull s10 = ((const ull*)&hxn_s[am][32 + aq*8])[0];
            const ull s11 = ((const ull*)&hxn_s[am][32 + aq*8])[1];
            ull* d0 = exw + ((size_t)(2*cbk)*64   + lane)*2;
            ull* d1 = exw + ((size_t)(2*cbk+1)*64 + lane)*2;
            __hip_atomic_store(d0,   s00, __ATOMIC_RELAXED, ASCOPE);
            __hip_atomic_store(d0+1, s01, __ATOMIC_RELAXED, ASCOPE);
            __hip_atomic_store(d1,   s10, __ATOMIC_RELAXED, ASCOPE);
            __hip_atomic_store(d1+1, s11, __ATOMIC_RELAXED, ASCOPE);
            // z partials: lane -> (row zr, 16-col group zc); pair-tree over zc
            const int zr = lane >> 2, zc = lane & 3;
            float sz = 0.f;
            #pragma unroll
            for (int i = 0; i < 16; ++i)
                sz += bf2f(hxn_s[zr][zc*16 + i]) * wp_s[zc*16 + i];
            sz += __shfl_xor(sz, 1);
            sz += __shfl_xor(sz, 2);
            if (zc == 0)
                __hip_atomic_store(&zpw[zr*CB + cbk], sz, __ATOMIC_RELAXED, ASCOPE);
            // completion-ack of all prior vmem stores, THEN flag issue => happens-before
            asm volatile("s_waitcnt vmcnt(0)" ::: "memory");
            if (lane == 0)
                __hip_atomic_store(&flags[rg*16 + cbk], it + 1u, __ATOMIC_RELAXED, ASCOPE);
        }
        ++it;
    };

    for (int t = 0; t < TT; ++t) {
        // ---- stage x_t slice as bf16 A-frags ----
        #pragma unroll
        for (int j = 0; j < 2; ++j) {
            const int s = j*NTH + tid;       // ch = s>>6, slot lane = lane
            const int ch = s >> 6;
            const float* xb = x + ((size_t)t*BB + r0 + am)*DD + ch*32 + aq*8;
            float4 a0 = *(const float4*)xb;
            float4 a1 = *(const float4*)(xb + 4);
            union { s16x8 v; unsigned short e[8]; } u;
            u.e[0]=f2bf(a0.x); u.e[1]=f2bf(a0.y); u.e[2]=f2bf(a0.z); u.e[3]=f2bf(a0.w);
            u.e[4]=f2bf(a1.x); u.e[5]=f2bf(a1.y); u.e[6]=f2bf(a1.z); u.e[7]=f2bf(a1.w);
            xA_s[s] = u.v;
        }
        __syncthreads();   // T0: guards A_s (init/finalize) + xA_s writes

        // ---- xi tile per wave: x @ Wih^T + bias (MFMA, registers) ----
        f32x4 xi;
        {
            f32x4 a = {0.f,0.f,0.f,0.f};
            #pragma unroll
            for (int ch = 0; ch < 8; ++ch)
                a = __builtin_amdgcn_mfma_f32_16x16x32_bf16(
                        xA_s[ch*64 + lane], WB_s[(CT*8 + ch)*64 + lane], a, 0, 0, 0);
            xi[0]=a[0]+bs_lane; xi[1]=a[1]+bs_lane; xi[2]=a[2]+bs_lane; xi[3]=a[3]+bs_lane;
        }

        // per-lane replicated row state (row = am; 16 replicas compute identically)
        float ahx[48];
        #pragma unroll
        for (int q = 0; q < 48; ++q) ahx[q] = 0.f;
        float ah = 0.f, sc = 0.f, spc = 0.f;
        int act = 1;

        // ---- k=0 matvec from LDS A_s (hx carried from finalize; flag col = 0) ----
        {
            f32x4 acc = xi;
            #pragma unroll
            for (int ch = 0; ch < NCH; ++ch)
                acc = __builtin_amdgcn_mfma_f32_16x16x32_bf16(
                        A_s[ch*64 + lane], Breg[ch], acc, 0, 0, 0);
            #pragma unroll
            for (int r = 0; r < 4; ++r)
                hxn_s[aq*4 + r][CT*16 + am] = f2bf(fast_tanh(acc[r]));
        }
        __syncthreads();   // S1: hxn_s ready for wave0 publish; prior A_s reads done
        publish();

        // ---- ponder exchange/consume loop (iteration pk consumes publish it-1) ----
        for (int pk = 1; ; ++pk) {
            // wave 0: INCREMENTAL consume. As each producer's flag arrives, pull its
            // 2 hx-chunks + z-partials (proven agent atomics) and deposit into LDS.
            // By the time the last flag lands, 11/12 of the exchange is already
            // staged; waves 1-3 are parked at S2 (zero vmem traffic).
            if (CT == 0) {
                const unsigned parR = (it - 1u) & 1u;
                const ull*   exr = hxe + (size_t)(rg*2 + parR) * (NCH*64*2);
                const float* zpr = zpt + (size_t)(rg*2 + parR) * (RPG*CB);
                const int pi = lane % 12;
                unsigned done_m = 0;
                while (done_m != 0xfffu) {
                    const unsigned v =
                        __hip_atomic_load(&flags[rg*16 + pi], __ATOMIC_RELAXED, ASCOPE);
                    ull rdy = __ballot((lane < 12) && (v >= it) &&
                                       !((done_m >> lane) & 1u));
                    while (rdy) {
                        const int p = (int)__builtin_ctzll(rdy);
                        rdy &= rdy - 1;
                        done_m |= 1u << p;
                        const ull* s0 = exr + ((size_t)(2*p)*64   + lane)*2;
                        const ull* s1 = exr + ((size_t)(2*p+1)*64 + lane)*2;
                        AU c0, c1;
                        c0.u[0] = __hip_atomic_load(s0,   __ATOMIC_RELAXED, ASCOPE);
                        c0.u[1] = __hip_atomic_load(s0+1, __ATOMIC_RELAXED, ASCOPE);
                        c1.u[0] = __hip_atomic_load(s1,   __ATOMIC_RELAXED, ASCOPE);
                        c1.u[1] = __hip_atomic_load(s1+1, __ATOMIC_RELAXED, ASCOPE);
                        float zl = 0.f;
                        if (lane < RPG)
                            zl = __uint_as_float(__hip_atomic_load(
                                     (const unsigned*)&zpr[lane*CB + p],
                                     __ATOMIC_RELAXED, ASCOPE));
                        A_s[(2*p)*64   + lane] = c0.s;
                        A_s[(2*p+1)*64 + lane] = c1.s;
                        if (lane < RPG) zred_s[lane][p] = zl;
                    }
                }
            }
            __syncthreads();   // S2: A_s + zred_s fully staged; waves 1-3 resume

            // z sum from LDS -- same association tree as always
            float zf[12];
            #pragma unroll
            for (int k = 0; k < 12; ++k) zf[k] = zred_s[am][k];
            const float zA = (zf[0]+zf[1]) + (zf[2]+zf[3]);
            const float zB = (zf[4]+zf[5]) + (zf[6]+zf[7]);
            const float zC = (zf[8]+zf[9]) + (zf[10]+zf[11]);
            const float z  = (zA + zB) + zC;
            const float h  = 1.f / (1.f + __expf(-(z + bp0)));
            float w1 = 0.f;
            if (act) {
                spc = -ah;
                ah += h;
                w1 = 1.f + (h - fmaxf(ah - 1.f, 0.f));   // 1 + p
                sc += 1.f;
                act = (ah < 0.99f) ? 1 : 0;               // 1-EPS == 0.99f exactly
            }
            const bool done = __all(act == 0) || (pk == MAXP);   // block-uniform

            if (done) {
                // accumulate own 6 chunks straight from LDS (same values as exchange)
                #pragma unroll
                for (int j = 0; j < 6; ++j) {
                    AU u; u.s = A_s[(j*4 + CT)*64 + lane];
                    #pragma unroll
                    for (int i = 0; i < 8; ++i)
                        ahx[j*8 + i] += w1 * bf2f(u.e[i]);
                }
                break;
            }

            // matvec step pk: MFMA directly from staged A_s (no S3 needed)
            f32x4 acc = xi;
            #pragma unroll
            for (int ch = 0; ch < NCH; ++ch)
                acc = __builtin_amdgcn_mfma_f32_16x16x32_bf16(
                        A_s[ch*64 + lane], Breg[ch], acc, 0, 0, 0);
            // ahx accumulation (LDS re-reads CSE with MFMA operand reads; hides
            // under the MFMA chain)
            #pragma unroll
            for (int j = 0; j < 6; ++j) {
                AU u; u.s = A_s[(j*4 + CT)*64 + lane];
                #pragma unroll
                for (int i = 0; i < 8; ++i)
                    ahx[j*8 + i] += w1 * bf2f(u.e[i]);
            }
            #pragma unroll
            for (int r = 0; r < 4; ++r)
                hxn_s[aq*4 + r][CT*16 + am] = f2bf(fast_tanh(acc[r] + wfl));
            __syncthreads();   // S1: hxn_s ready + A_s reads done before next consume
            publish();
        }

        // ---- finalize t: hx_out = accum_hx / sc (all per-lane; barrier-free) ----
        const float inv = 1.f / sc;
        pc += spc;
        if (cbk == 0 && tid < RPG) out[OFF_STEPS + (size_t)t*BB + r0 + tid] = sc;
        #pragma unroll
        for (int j = 0; j < 6; ++j) {
            const int ch = j*4 + CT;
            float o[8];
            #pragma unroll
            for (int i = 0; i < 8; ++i) o[i] = ahx[j*8 + i] * inv;
            union { s16x8 v; unsigned short e[8]; } u;
            #pragma unroll
            for (int i = 0; i < 8; ++i) u.e[i] = f2bf(o[i]);
            A_s[ch*64 + lane] = u.v;   // next t's hx(k=0); guarded by next T0 barrier
            if (cbk == 0) {
                float* op = out + ((size_t)t*BB + r0 + am)*HH + ch*32 + aq*8;
                *(float4*)op       = make_float4(o[0], o[1], o[2], o[3]);
                *(float4*)(op + 4) = make_float4(o[4], o[5], o[6], o[7]);
                if (t == TT-1) {
                    float* lp = out + OFF_LAST + (size_t)(r0 + am)*HH + ch*32 + aq*8;
                    *(float4*)lp       = make_float4(o[0], o[1], o[2], o[3]);
                    *(float4*)(lp + 4) = make_float4(o[4], o[5], o[6], o[7]);
                }
            }
        }
    }
    if (cbk == 0 && tid < RPG) out[OFF_PCOST + r0 + tid] = pc;
}

extern "C" void kernel_launch(void* const* d_in, const int* in_sizes, int n_in,
                              void* d_out, int out_size, void* d_ws, size_t ws_size,
                              hipStream_t stream) {
    const float* x   = (const float*)d_in[0];
    const float* Wih = (const float*)d_in[1];
    const float* Whh = (const float*)d_in[2];
    const float* bih = (const float*)d_in[3];
    const float* bhh = (const float*)d_in[4];
    const float* wpv = (const float*)d_in[5];
    const float* bp  = (const float*)d_in[6];
    float* out = (float*)d_out;

    // ws: [0,4096) flags (zeroed); [4096,+393216) hx exchange (bf16 A-frag,
    // double-parity per rowgroup); then z partials (6144 B)
    unsigned* flags = (unsigned*)d_ws;
    ull*      hxe   = (ull*)((char*)d_ws + 4096);
    float*    zpt   = (float*)((char*)d_ws + 4096 + (size_t)RG*2*NCH*64*16);

    hipMemsetAsync(d_ws, 0, 4096, stream);
    act_kernel<<<dim3(RG*CB), dim3(NTH), 0, stream>>>(
        x, Wih, Whh, bih, bhh, wpv, bp, out, flags, hxe, zpt);
}

// Round 8
// 486.031 us; speedup vs baseline: 1.1749x; 1.1749x over previous
//
#include <hip/hip_runtime.h>
#include <math.h>

// Problem constants
#define TT 32
#define BB 128
#define DD 256
#define HH 768
#define MAXP 8

// Decomposition: 8 rowgroups (16 rows) x 12 col-blocks (64 cols), 256 thr (4 waves = 4 col-tiles)
#define RG   8
#define RPG  16
#define CB   12
#define CS   64
#define NTH  256
#define NCH  24    // K chunks of 32
#define NBUF 4     // parity ring depth (sentinel protocol needs >=3; 4 for pow2)

#define OFF_LAST  ((size_t)TT * BB * HH)
#define OFF_PCOST (OFF_LAST + (size_t)BB * HH)
#define OFF_STEPS (OFF_PCOST + BB)

#define ASCOPE __HIP_MEMORY_SCOPE_AGENT
#define SENT   0xFFFFFFFFFFFFFFFFull   // 4x bf16 NaN / 2x f32 NaN: unreachable by tanh/z data

typedef __attribute__((ext_vector_type(8))) short s16x8;
typedef __attribute__((ext_vector_type(4))) float f32x4;
typedef unsigned long long ull;

static __device__ __forceinline__ unsigned short f2bf(float f) {
    unsigned u = __float_as_uint(f);
    u = (u + 0x7fffu + ((u >> 16) & 1u)) >> 16;   // RNE
    return (unsigned short)u;
}
static __device__ __forceinline__ float bf2f(unsigned short h) {
    return __uint_as_float(((unsigned)h) << 16);
}
// bf16-target precision is 2^-9; __expf error ~1e-6 is invisible.
static __device__ __forceinline__ float fast_tanh(float v) {
    return 1.f - 2.f / (__expf(2.f * v) + 1.f);
}

__launch_bounds__(NTH, 1)
__global__ void act_kernel(const float* __restrict__ x,
                           const float* __restrict__ Wih,
                           const float* __restrict__ Whh,
                           const float* __restrict__ bih,
                           const float* __restrict__ bhh,
                           const float* __restrict__ wpv,
                           const float* __restrict__ bp,
                           float* __restrict__ out,
                           unsigned* __restrict__ flags,
                           ull* __restrict__ hxe,
                           float* __restrict__ zpt)
{
    const int tid  = threadIdx.x;
    const int rg   = blockIdx.x & 7;     // rowgroup -> XCD (perf heuristic only)
    const int cbk  = blockIdx.x >> 3;    // col-block [0,12)
    const int r0   = rg * RPG;
    const int c0   = cbk * CS;
    const int CT   = tid >> 6;           // wave = col-tile [0,4)
    const int lane = tid & 63;
    const int am   = lane & 15;          // A-frag row / C-frag col
    const int aq   = lane >> 4;

    // clear-word mapping: tid -> one 8B word of this block's 2KB exchange slice
    const int pchd  = tid >> 7;                      // chunk-half [0,2)
    const int pl    = (tid & 127) >> 1;              // slot lane [0,64)
    const int phalf = tid & 1;                       // ull half
    const size_t pword = ((size_t)(2*cbk + pchd)*64 + pl)*2 + phalf;

    // LDS ~68 KB
    __shared__ s16x8 A_s[NCH * 64];        // current hx A-frags (finalize or exchange)
    __shared__ s16x8 WB_s[4 * 8 * 64];     // Wih B-frags (32 KB)
    __shared__ s16x8 xA_s[8 * 64];         // x_t A-frags (8 KB)
    __shared__ __align__(16) unsigned short hxn_s[RPG][72];   // new hx slice, bf16 (pad 72)
    __shared__ float wp_s[CS];

    // ---- init: Whh B-frags -> permanent VGPRs (96) ----
    s16x8 Breg[NCH];
    {
        const float* wr = Whh + (size_t)(c0 + CT*16 + am) * HH + aq*8;
        for (int ch = 0; ch < NCH; ++ch) {
            float4 a0 = *(const float4*)(wr + ch*32);
            float4 a1 = *(const float4*)(wr + ch*32 + 4);
            union { s16x8 v; unsigned short e[8]; } u;
            u.e[0]=f2bf(a0.x); u.e[1]=f2bf(a0.y); u.e[2]=f2bf(a0.z); u.e[3]=f2bf(a0.w);
            u.e[4]=f2bf(a1.x); u.e[5]=f2bf(a1.y); u.e[6]=f2bf(a1.z); u.e[7]=f2bf(a1.w);
            Breg[ch] = u.v;
        }
    }
    // Wih B-frags -> LDS (row stride 257 unaligned: scalar loads, init-only)
    for (int ch = 0; ch < 8; ++ch) {
        const float* wr = Wih + (size_t)(c0 + CT*16 + am) * (DD+1) + ch*32 + aq*8;
        union { s16x8 v; unsigned short e[8]; } u;
        #pragma unroll
        for (int j = 0; j < 8; ++j) u.e[j] = f2bf(wr[j]);
        WB_s[(CT*8 + ch)*64 + lane] = u.v;
    }
    if (tid < CS) wp_s[tid] = wpv[c0 + tid];
    // per-lane column constants (col = c0 + CT*16 + am)
    const int myc = c0 + CT*16 + am;
    const float bs_lane = bih[myc] + bhh[myc];
    const float wfl     = Wih[(size_t)myc*(DD+1) + DD];   // ponder-flag column
    const float bp0     = bp[0];
    {
        s16x8 z8 = {0,0,0,0,0,0,0,0};
        #pragma unroll
        for (int j = 0; j < 6; ++j) A_s[j*NTH + tid] = z8;   // hx0 = 0
    }

    float pc = 0.f;     // per-lane pcost for row am
    unsigned it = 0;    // number of publishes completed by this block

    // Publish round r=it: wave 0 fires data + z + flag back-to-back with NO drain
    // (consumers sentinel-validate). Then ALL waves fire the parity-(r+2) clears;
    // their acks hide under wave0's spin / waves 1-3's barrier-park, and they are
    // drained by the next __syncthreads -- >=2 barriers before flag(r+1), which is
    // what gates any consumer of that parity.
    auto publish = [&]() {
        const unsigned par = it & (NBUF-1);
        if (CT == 0) {
            ull*   exw = hxe + (size_t)(rg*NBUF + par) * (NCH*64*2);
            float* zpw = zpt + (size_t)(rg*NBUF + par) * (RPG*CB);
            const ull s00 = ((const ull*)&hxn_s[am][aq*8])[0];
            const ull s01 = ((const ull*)&hxn_s[am][aq*8])[1];
            const ull s10 = ((const ull*)&hxn_s[am][32 + aq*8])[0];
            const ull s11 = ((const ull*)&hxn_s[am][32 + aq*8])[1];
            ull* d0 = exw + ((size_t)(2*cbk)*64   + lane)*2;
            ull* d1 = exw + ((size_t)(2*cbk+1)*64 + lane)*2;
            __hip_atomic_store(d0,   s00, __ATOMIC_RELAXED, ASCOPE);
            __hip_atomic_store(d0+1, s01, __ATOMIC_RELAXED, ASCOPE);
            __hip_atomic_store(d1,   s10, __ATOMIC_RELAXED, ASCOPE);
            __hip_atomic_store(d1+1, s11, __ATOMIC_RELAXED, ASCOPE);
            // z partials: lane -> (row zr, 16-col group zc); pair-tree over zc
            const int zr = lane >> 2, zc = lane & 3;
            float sz = 0.f;
            #pragma unroll
            for (int i = 0; i < 16; ++i)
                sz += bf2f(hxn_s[zr][zc*16 + i]) * wp_s[zc*16 + i];
            sz += __shfl_xor(sz, 1);
            sz += __shfl_xor(sz, 2);
            if (zc == 0)
                __hip_atomic_store(&zpw[zr*CB + cbk], sz, __ATOMIC_RELAXED, ASCOPE);
            // NO drain: flag fires immediately; sentinel validation covers reordering
            if (lane == 0)
                __hip_atomic_store(&flags[rg*16 + cbk], it + 1u, __ATOMIC_RELAXED, ASCOPE);
        }
        ++it;
        // sentinel-clear own slice of parity (r+2): holds round r-2, consumed by all
        // (flags(r-1), observed before this publish, imply consume(r-2) completed)
        {
            const unsigned cpar = (it + 1u) & (NBUF-1);
            ull*   exc = hxe + (size_t)(rg*NBUF + cpar) * (NCH*64*2);
            float* zpc = zpt + (size_t)(rg*NBUF + cpar) * (RPG*CB);
            __hip_atomic_store(exc + pword, SENT, __ATOMIC_RELAXED, ASCOPE);
            if (tid < RPG)
                __hip_atomic_store((unsigned*)&zpc[tid*CB + cbk], 0xffffffffu,
                                   __ATOMIC_RELAXED, ASCOPE);
        }
    };

    for (int t = 0; t < TT; ++t) {
        // ---- stage x_t slice as bf16 A-frags ----
        #pragma unroll
        for (int j = 0; j < 2; ++j) {
            const int s = j*NTH + tid;       // ch = s>>6, slot lane = lane
            const int ch = s >> 6;
            const float* xb = x + ((size_t)t*BB + r0 + am)*DD + ch*32 + aq*8;
            float4 a0 = *(const float4*)xb;
            float4 a1 = *(const float4*)(xb + 4);
            union { s16x8 v; unsigned short e[8]; } u;
            u.e[0]=f2bf(a0.x); u.e[1]=f2bf(a0.y); u.e[2]=f2bf(a0.z); u.e[3]=f2bf(a0.w);
            u.e[4]=f2bf(a1.x); u.e[5]=f2bf(a1.y); u.e[6]=f2bf(a1.z); u.e[7]=f2bf(a1.w);
            xA_s[s] = u.v;
        }
        __syncthreads();   // T0: guards A_s (init/finalize) + xA_s writes; drains clears

        // ---- xi tile per wave: x @ Wih^T + bias (MFMA, registers) ----
        f32x4 xi;
        {
            f32x4 a = {0.f,0.f,0.f,0.f};
            #pragma unroll
            for (int ch = 0; ch < 8; ++ch)
                a = __builtin_amdgcn_mfma_f32_16x16x32_bf16(
                        xA_s[ch*64 + lane], WB_s[(CT*8 + ch)*64 + lane], a, 0, 0, 0);
            xi[0]=a[0]+bs_lane; xi[1]=a[1]+bs_lane; xi[2]=a[2]+bs_lane; xi[3]=a[3]+bs_lane;
        }

        // per-lane replicated row state (row = am; 16 replicas compute identically)
        float ahx[48];
        #pragma unroll
        for (int q = 0; q < 48; ++q) ahx[q] = 0.f;
        float ah = 0.f, sc = 0.f, spc = 0.f;
        int act = 1;

        // ---- k=0 matvec from LDS A_s (hx carried from finalize; flag col = 0) ----
        {
            f32x4 acc = xi;
            #pragma unroll
            for (int ch = 0; ch < NCH; ++ch)
                acc = __builtin_amdgcn_mfma_f32_16x16x32_bf16(
                        A_s[ch*64 + lane], Breg[ch], acc, 0, 0, 0);
            #pragma unroll
            for (int r = 0; r < 4; ++r)
                hxn_s[aq*4 + r][CT*16 + am] = f2bf(fast_tanh(acc[r]));
        }
        __syncthreads();   // S1: hxn_s ready for wave0 publish
        publish();

        // ---- ponder exchange/consume loop (iteration pk consumes publish it-1) ----
        for (int pk = 1; ; ++pk) {
            // lone spinner on flags; waves 1-3 parked at S2 (their clear acks drain
            // at S2 entry, in parallel with the spin -- fully hidden)
            if (CT == 0) {
                const int pi = lane % 12;
                unsigned v;
                do { v = __hip_atomic_load(&flags[rg*16 + pi], __ATOMIC_RELAXED, ASCOPE); }
                while (!__all((int)(v >= it)));
            }
            __syncthreads();   // S2

            const unsigned parR = (it - 1u) & (NBUF-1);
            const ull* exr = hxe + (size_t)(rg*NBUF + parR) * (NCH*64*2);
            const ull* zb  = (const ull*)(zpt + (size_t)(rg*NBUF + parR) * (RPG*CB) + am*CB);

            // batched cooperative consume (full MLP: 18 loads in flight per thread),
            // sentinel-validated; first pass succeeds except under flag/data reorder
            ull clo[6], chi[6], zu[6];
            unsigned hok = 0, zok = 0;
            for (;;) {
                #pragma unroll
                for (int j = 0; j < 6; ++j) {
                    const ull* src = exr + ((size_t)((j*4 + CT)*64 + lane))*2;
                    if (!(hok & (1u << (2*j)))) {
                        clo[j] = __hip_atomic_load(src, __ATOMIC_RELAXED, ASCOPE);
                        if (clo[j] != SENT) hok |= 1u << (2*j);
                    }
                    if (!(hok & (1u << (2*j+1)))) {
                        chi[j] = __hip_atomic_load(src+1, __ATOMIC_RELAXED, ASCOPE);
                        if (chi[j] != SENT) hok |= 1u << (2*j+1);
                    }
                }
                #pragma unroll
                for (int j = 0; j < 6; ++j) {
                    if (!(zok & (1u << j))) {
                        zu[j] = __hip_atomic_load(zb + j, __ATOMIC_RELAXED, ASCOPE);
                        // each 4B half is one producer's store; both must be valid
                        if ((unsigned)(zu[j] & 0xffffffffu) != 0xffffffffu &&
                            (unsigned)(zu[j] >> 32)         != 0xffffffffu)
                            zok |= 1u << j;
                    }
                }
                if (__all((int)(hok == 0xfffu && zok == 0x3fu))) break;
            }

            // redistribute own chunks into LDS A-frags (z math hides under this)
            #pragma unroll
            for (int j = 0; j < 6; ++j) {
                union { ull u[2]; s16x8 v; } cv;
                cv.u[0] = clo[j]; cv.u[1] = chi[j];
                A_s[(j*4 + CT)*64 + lane] = cv.v;
            }

            // z sum -- same association tree as always: ((0..3)+(4..7))+(8..11)
            float zf[12];
            #pragma unroll
            for (int j = 0; j < 6; ++j) {
                zf[2*j]   = __uint_as_float((unsigned)(zu[j] & 0xffffffffu));
                zf[2*j+1] = __uint_as_float((unsigned)(zu[j] >> 32));
            }
            const float zA = (zf[0]+zf[1]) + (zf[2]+zf[3]);
            const float zB = (zf[4]+zf[5]) + (zf[6]+zf[7]);
            const float zC = (zf[8]+zf[9]) + (zf[10]+zf[11]);
            const float z  = (zA + zB) + zC;
            const float h  = 1.f / (1.f + __expf(-(z + bp0)));
            float w1 = 0.f;
            if (act) {
                spc = -ah;
                ah += h;
                w1 = 1.f + (h - fmaxf(ah - 1.f, 0.f));   // 1 + p
                sc += 1.f;
                act = (ah < 0.99f) ? 1 : 0;               // 1-EPS == 0.99f exactly
            }
            const bool done = __all(act == 0) || (pk == MAXP);   // block-uniform

            if (done) {
                #pragma unroll
                for (int j = 0; j < 6; ++j) {
                    #pragma unroll
                    for (int i = 0; i < 4; ++i) {
                        ahx[j*8 + i]     += w1 * bf2f((unsigned short)(clo[j] >> (16*i)));
                        ahx[j*8 + 4 + i] += w1 * bf2f((unsigned short)(chi[j] >> (16*i)));
                    }
                }
                break;
            }
            __syncthreads();   // S3: A_s fully redistributed

            // matvec step pk: MFMA from LDS (frozen rows' outputs are w1=0-gated)
            f32x4 acc = xi;
            #pragma unroll
            for (int ch = 0; ch < NCH; ++ch)
                acc = __builtin_amdgcn_mfma_f32_16x16x32_bf16(
                        A_s[ch*64 + lane], Breg[ch], acc, 0, 0, 0);
            // ahx accumulation (independent VALU, hides under the MFMA chain)
            #pragma unroll
            for (int j = 0; j < 6; ++j) {
                #pragma unroll
                for (int i = 0; i < 4; ++i) {
                    ahx[j*8 + i]     += w1 * bf2f((unsigned short)(clo[j] >> (16*i)));
                    ahx[j*8 + 4 + i] += w1 * bf2f((unsigned short)(chi[j] >> (16*i)));
                }
            }
            #pragma unroll
            for (int r = 0; r < 4; ++r)
                hxn_s[aq*4 + r][CT*16 + am] = f2bf(fast_tanh(acc[r] + wfl));
            __syncthreads();   // S1: hxn_s ready for next publish
            publish();
        }

        // ---- finalize t: hx_out = accum_hx / sc (all per-lane; barrier-free) ----
        const float inv = 1.f / sc;
        pc += spc;
        if (cbk == 0 && tid < RPG) out[OFF_STEPS + (size_t)t*BB + r0 + tid] = sc;
        #pragma unroll
        for (int j = 0; j < 6; ++j) {
            const int ch = j*4 + CT;
            float o[8];
            #pragma unroll
            for (int i = 0; i < 8; ++i) o[i] = ahx[j*8 + i] * inv;
            union { s16x8 v; unsigned short e[8]; } u;
            #pragma unroll
            for (int i = 0; i < 8; ++i) u.e[i] = f2bf(o[i]);
            A_s[ch*64 + lane] = u.v;   // next t's hx(k=0); guarded by next T0 barrier
            if (cbk == 0) {
                float* op = out + ((size_t)t*BB + r0 + am)*HH + ch*32 + aq*8;
                *(float4*)op       = make_float4(o[0], o[1], o[2], o[3]);
                *(float4*)(op + 4) = make_float4(o[4], o[5], o[6], o[7]);
                if (t == TT-1) {
                    float* lp = out + OFF_LAST + (size_t)(r0 + am)*HH + ch*32 + aq*8;
                    *(float4*)lp       = make_float4(o[0], o[1], o[2], o[3]);
                    *(float4*)(lp + 4) = make_float4(o[4], o[5], o[6], o[7]);
                }
            }
        }
    }
    if (cbk == 0 && tid < RPG) out[OFF_PCOST + r0 + tid] = pc;
}

extern "C" void kernel_launch(void* const* d_in, const int* in_sizes, int n_in,
                              void* d_out, int out_size, void* d_ws, size_t ws_size,
                              hipStream_t stream) {
    const float* x   = (const float*)d_in[0];
    const float* Wih = (const float*)d_in[1];
    const float* Whh = (const float*)d_in[2];
    const float* bih = (const float*)d_in[3];
    const float* bhh = (const float*)d_in[4];
    const float* wpv = (const float*)d_in[5];
    const float* bp  = (const float*)d_in[6];
    float* out = (float*)d_out;

    // ws: [0,4096) flags (zeroed); [4096, +786432) hx exchange (bf16 A-frag words,
    // 4-deep parity ring per rowgroup, sentinel-filled); then z partials (24576 B,
    // sentinel-filled)
    unsigned* flags = (unsigned*)d_ws;
    ull*      hxe   = (ull*)((char*)d_ws + 4096);
    float*    zpt   = (float*)((char*)d_ws + 4096 + (size_t)RG*NBUF*NCH*64*16);

    hipMemsetAsync(d_ws, 0, 4096, stream);
    hipMemsetAsync((char*)d_ws + 4096, 0xFF,
                   (size_t)RG*NBUF*NCH*64*16 + (size_t)RG*NBUF*RPG*CB*4, stream);
    act_kernel<<<dim3(RG*CB), dim3(NTH), 0, stream>>>(
        x, Wih, Whh, bih, bhh, wpv, bp, out, flags, hxe, zpt);
}

// Round 9
// 403.802 us; speedup vs baseline: 1.4142x; 1.2036x over previous
//
#include <hip/hip_runtime.h>
#include <math.h>

// Problem constants
#define TT 32
#define BB 128
#define DD 256
#define HH 768
#define MAXP 8

// Decomposition: 8 rowgroups (16 rows) x 12 col-blocks (64 cols), 256 thr (4 waves = 4 col-tiles)
#define RG   8
#define RPG  16
#define CB   12
#define CS   64
#define NTH  256
#define NCH  24    // K chunks of 32
#define NBUF 4     // inbox parity ring depth
#define HXW  (NCH*64*2)   // 3072 x 8B words per inbox parity (24.5 KB)
#define ZWF  (RPG*CB)     // 192 z floats per inbox parity

#define OFF_LAST  ((size_t)TT * BB * HH)
#define OFF_PCOST (OFF_LAST + (size_t)BB * HH)
#define OFF_STEPS (OFF_PCOST + BB)

#define ASCOPE __HIP_MEMORY_SCOPE_AGENT
#define SENT   0xFFFFFFFFFFFFFFFFull   // 4x bf16 NaN / 2x f32 NaN: unreachable by tanh/z data

typedef __attribute__((ext_vector_type(8))) short s16x8;
typedef __attribute__((ext_vector_type(4))) float f32x4;
typedef unsigned long long ull;

static __device__ __forceinline__ unsigned short f2bf(float f) {
    unsigned u = __float_as_uint(f);
    u = (u + 0x7fffu + ((u >> 16) & 1u)) >> 16;   // RNE
    return (unsigned short)u;
}
static __device__ __forceinline__ float bf2f(unsigned short h) {
    return __uint_as_float(((unsigned)h) << 16);
}
// bf16-target precision is 2^-9; __expf error ~1e-6 is invisible.
static __device__ __forceinline__ float fast_tanh(float v) {
    return 1.f - 2.f / (__expf(2.f * v) + 1.f);
}

__launch_bounds__(NTH, 1)
__global__ void act_kernel(const float* __restrict__ x,
                           const float* __restrict__ Wih,
                           const float* __restrict__ Whh,
                           const float* __restrict__ bih,
                           const float* __restrict__ bhh,
                           const float* __restrict__ wpv,
                           const float* __restrict__ bp,
                           float* __restrict__ out,
                           ull* __restrict__ hxin,
                           float* __restrict__ zin)
{
    const int tid  = threadIdx.x;
    const int rg   = blockIdx.x & 7;     // rowgroup -> XCD (perf heuristic only)
    const int cbk  = blockIdx.x >> 3;    // col-block [0,12)
    const int r0   = rg * RPG;
    const int c0   = cbk * CS;
    const int CT   = tid >> 6;           // wave = col-tile [0,4)
    const int lane = tid & 63;
    const int am   = lane & 15;          // A-frag row / C-frag col
    const int aq   = lane >> 4;

    // LDS ~68 KB
    __shared__ s16x8 A_s[NCH * 64];        // current hx A-frags (finalize or exchange)
    __shared__ s16x8 WB_s[4 * 8 * 64];     // Wih B-frags (32 KB)
    __shared__ s16x8 xA_s[8 * 64];         // x_t A-frags (8 KB)
    __shared__ __align__(16) unsigned short hxn_s[RPG][72];   // new hx slice, bf16 (pad 72)
    __shared__ float wp_s[CS];

    // ---- init: Whh B-frags -> permanent VGPRs (96) ----
    s16x8 Breg[NCH];
    {
        const float* wr = Whh + (size_t)(c0 + CT*16 + am) * HH + aq*8;
        for (int ch = 0; ch < NCH; ++ch) {
            float4 a0 = *(const float4*)(wr + ch*32);
            float4 a1 = *(const float4*)(wr + ch*32 + 4);
            union { s16x8 v; unsigned short e[8]; } u;
            u.e[0]=f2bf(a0.x); u.e[1]=f2bf(a0.y); u.e[2]=f2bf(a0.z); u.e[3]=f2bf(a0.w);
            u.e[4]=f2bf(a1.x); u.e[5]=f2bf(a1.y); u.e[6]=f2bf(a1.z); u.e[7]=f2bf(a1.w);
            Breg[ch] = u.v;
        }
    }
    // Wih B-frags -> LDS (row stride 257 unaligned: scalar loads, init-only)
    for (int ch = 0; ch < 8; ++ch) {
        const float* wr = Wih + (size_t)(c0 + CT*16 + am) * (DD+1) + ch*32 + aq*8;
        union { s16x8 v; unsigned short e[8]; } u;
        #pragma unroll
        for (int j = 0; j < 8; ++j) u.e[j] = f2bf(wr[j]);
        WB_s[(CT*8 + ch)*64 + lane] = u.v;
    }
    if (tid < CS) wp_s[tid] = wpv[c0 + tid];
    // per-lane column constants (col = c0 + CT*16 + am)
    const int myc = c0 + CT*16 + am;
    const float bs_lane = bih[myc] + bhh[myc];
    const float wfl     = Wih[(size_t)myc*(DD+1) + DD];   // ponder-flag column
    const float bp0     = bp[0];
    {
        s16x8 z8 = {0,0,0,0,0,0,0,0};
        #pragma unroll
        for (int j = 0; j < 6; ++j) A_s[j*NTH + tid] = z8;   // hx0 = 0
    }

    float pc = 0.f;     // per-lane pcost for row am
    unsigned it = 0;    // number of publishes completed by this block

    // Publish round r=it: PUSH this block's hx slice + z partials into ALL 12
    // consumers' inboxes (fire-and-forget agent atomics; consumers sentinel-validate,
    // so no drain and no flag). Wave w pushes to consumers {3w..3w+2}; every wave
    // computes the z tree redundantly from hxn_s. Then all threads sentinel-clear
    // this block's OWN inbox parity (r+2) -- it holds round r-2, consumed by us
    // before we published r-1; producers write round r+2 there only after consuming
    // our r+1 publish, and our clears drain at the barrier before that publish.
    auto publish = [&]() {
        const unsigned par = it & (NBUF-1);
        // z partials: lane -> (row zr, 16-col group zc); pair-tree over zc
        const int zr = lane >> 2, zc = lane & 3;
        float sz = 0.f;
        #pragma unroll
        for (int i = 0; i < 16; ++i)
            sz += bf2f(hxn_s[zr][zc*16 + i]) * wp_s[zc*16 + i];
        sz += __shfl_xor(sz, 1);
        sz += __shfl_xor(sz, 2);
        const ull s00 = ((const ull*)&hxn_s[am][aq*8])[0];
        const ull s01 = ((const ull*)&hxn_s[am][aq*8])[1];
        const ull s10 = ((const ull*)&hxn_s[am][32 + aq*8])[0];
        const ull s11 = ((const ull*)&hxn_s[am][32 + aq*8])[1];
        #pragma unroll
        for (int cc = 0; cc < 3; ++cc) {
            const int c = CT*3 + cc;
            ull*   exw = hxin + ((size_t)((rg*CB + c)*NBUF + par))*HXW;
            float* zpw = zin  + ((size_t)((rg*CB + c)*NBUF + par))*ZWF;
            ull* d0 = exw + ((size_t)(2*cbk)*64   + lane)*2;
            ull* d1 = exw + ((size_t)(2*cbk+1)*64 + lane)*2;
            __hip_atomic_store(d0,   s00, __ATOMIC_RELAXED, ASCOPE);
            __hip_atomic_store(d0+1, s01, __ATOMIC_RELAXED, ASCOPE);
            __hip_atomic_store(d1,   s10, __ATOMIC_RELAXED, ASCOPE);
            __hip_atomic_store(d1+1, s11, __ATOMIC_RELAXED, ASCOPE);
            if (zc == 0)
                __hip_atomic_store(&zpw[zr*CB + cbk], sz, __ATOMIC_RELAXED, ASCOPE);
        }
        ++it;
        // sentinel-clear own inbox parity (r+2) = (it+1)&3 after the increment
        const unsigned cpar = (it + 1u) & (NBUF-1);
        ull* exc = hxin + ((size_t)((rg*CB + cbk)*NBUF + cpar))*HXW;
        ull* zpc = (ull*)(zin + ((size_t)((rg*CB + cbk)*NBUF + cpar))*ZWF);
        #pragma unroll
        for (int k = 0; k < 12; ++k)
            __hip_atomic_store(exc + tid + k*NTH, SENT, __ATOMIC_RELAXED, ASCOPE);
        if (tid < 96)
            __hip_atomic_store(zpc + tid, SENT, __ATOMIC_RELAXED, ASCOPE);
    };

    for (int t = 0; t < TT; ++t) {
        // ---- stage x_t slice as bf16 A-frags ----
        #pragma unroll
        for (int j = 0; j < 2; ++j) {
            const int s = j*NTH + tid;       // ch = s>>6, slot lane = lane
            const int ch = s >> 6;
            const float* xb = x + ((size_t)t*BB + r0 + am)*DD + ch*32 + aq*8;
            float4 a0 = *(const float4*)xb;
            float4 a1 = *(const float4*)(xb + 4);
            union { s16x8 v; unsigned short e[8]; } u;
            u.e[0]=f2bf(a0.x); u.e[1]=f2bf(a0.y); u.e[2]=f2bf(a0.z); u.e[3]=f2bf(a0.w);
            u.e[4]=f2bf(a1.x); u.e[5]=f2bf(a1.y); u.e[6]=f2bf(a1.z); u.e[7]=f2bf(a1.w);
            xA_s[s] = u.v;
        }
        __syncthreads();   // T0: guards A_s (init/finalize) + xA_s writes

        // ---- xi tile per wave: x @ Wih^T + bias (MFMA, registers) ----
        f32x4 xi;
        {
            f32x4 a = {0.f,0.f,0.f,0.f};
            #pragma unroll
            for (int ch = 0; ch < 8; ++ch)
                a = __builtin_amdgcn_mfma_f32_16x16x32_bf16(
                        xA_s[ch*64 + lane], WB_s[(CT*8 + ch)*64 + lane], a, 0, 0, 0);
            xi[0]=a[0]+bs_lane; xi[1]=a[1]+bs_lane; xi[2]=a[2]+bs_lane; xi[3]=a[3]+bs_lane;
        }

        // per-lane replicated row state (row = am; 16 replicas compute identically)
        float ahx[48];
        #pragma unroll
        for (int q = 0; q < 48; ++q) ahx[q] = 0.f;
        float ah = 0.f, sc = 0.f, spc = 0.f;
        int act = 1;

        // ---- k=0 matvec from LDS A_s (hx carried from finalize; flag col = 0) ----
        {
            f32x4 acc = xi;
            #pragma unroll
            for (int ch = 0; ch < NCH; ++ch)
                acc = __builtin_amdgcn_mfma_f32_16x16x32_bf16(
                        A_s[ch*64 + lane], Breg[ch], acc, 0, 0, 0);
            #pragma unroll
            for (int r = 0; r < 4; ++r)
                hxn_s[aq*4 + r][CT*16 + am] = f2bf(fast_tanh(acc[r]));
        }
        __syncthreads();   // S1: hxn_s complete -> all waves may push
        publish();

        // ---- ponder exchange/consume loop (iteration pk consumes publish it-1) ----
        for (int pk = 1; ; ++pk) {
            const unsigned parR = (it - 1u) & (NBUF-1);
            const ull* exr = hxin + ((size_t)((rg*CB + cbk)*NBUF + parR))*HXW;
            const ull* zb  = (const ull*)(zin + ((size_t)((rg*CB + cbk)*NBUF + parR))*ZWF
                                          + am*CB);

            // sentinel-validated poll of OWN inbox: the poll IS the data read.
            // Attempt 1 issues the full 18-word batch (full MLP); retries reload
            // only still-sentinel words (exec-masked), s_sleep-backed off after
            // the 2nd miss to bound MALL traffic.
            ull clo[6], chi[6], zu[6];
            unsigned hok = 0, zok = 0;
            int tries = 0;
            for (;;) {
                #pragma unroll
                for (int j = 0; j < 6; ++j) {
                    const ull* src = exr + ((size_t)((j*4 + CT)*64 + lane))*2;
                    if (!(hok & (1u << (2*j)))) {
                        clo[j] = __hip_atomic_load(src, __ATOMIC_RELAXED, ASCOPE);
                        if (clo[j] != SENT) hok |= 1u << (2*j);
                    }
                    if (!(hok & (1u << (2*j+1)))) {
                        chi[j] = __hip_atomic_load(src+1, __ATOMIC_RELAXED, ASCOPE);
                        if (chi[j] != SENT) hok |= 1u << (2*j+1);
                    }
                }
                #pragma unroll
                for (int j = 0; j < 6; ++j) {
                    if (!(zok & (1u << j))) {
                        zu[j] = __hip_atomic_load(zb + j, __ATOMIC_RELAXED, ASCOPE);
                        // each 4B half is one producer's store; both must be valid
                        if ((unsigned)(zu[j] & 0xffffffffu) != 0xffffffffu &&
                            (unsigned)(zu[j] >> 32)         != 0xffffffffu)
                            zok |= 1u << j;
                    }
                }
                if (__all((int)(hok == 0xfffu && zok == 0x3fu))) break;
                if (++tries > 1) asm volatile("s_sleep 8");   // ~512 cy backoff
            }

            // redistribute own chunks into LDS A-frags (z math hides under this)
            #pragma unroll
            for (int j = 0; j < 6; ++j) {
                union { ull u[2]; s16x8 v; } cv;
                cv.u[0] = clo[j]; cv.u[1] = chi[j];
                A_s[(j*4 + CT)*64 + lane] = cv.v;
            }

            // z sum -- same association tree as always: ((0..3)+(4..7))+(8..11)
            float zf[12];
            #pragma unroll
            for (int j = 0; j < 6; ++j) {
                zf[2*j]   = __uint_as_float((unsigned)(zu[j] & 0xffffffffu));
                zf[2*j+1] = __uint_as_float((unsigned)(zu[j] >> 32));
            }
            const float zA = (zf[0]+zf[1]) + (zf[2]+zf[3]);
            const float zB = (zf[4]+zf[5]) + (zf[6]+zf[7]);
            const float zC = (zf[8]+zf[9]) + (zf[10]+zf[11]);
            const float z  = (zA + zB) + zC;
            const float h  = 1.f / (1.f + __expf(-(z + bp0)));
            float w1 = 0.f;
            if (act) {
                spc = -ah;
                ah += h;
                w1 = 1.f + (h - fmaxf(ah - 1.f, 0.f));   // 1 + p
                sc += 1.f;
                act = (ah < 0.99f) ? 1 : 0;               // 1-EPS == 0.99f exactly
            }
            const bool done = __all(act == 0) || (pk == MAXP);   // block-uniform

            if (done) {
                #pragma unroll
                for (int j = 0; j < 6; ++j) {
                    #pragma unroll
                    for (int i = 0; i < 4; ++i) {
                        ahx[j*8 + i]     += w1 * bf2f((unsigned short)(clo[j] >> (16*i)));
                        ahx[j*8 + 4 + i] += w1 * bf2f((unsigned short)(chi[j] >> (16*i)));
                    }
                }
                break;
            }
            __syncthreads();   // S3: A_s fully redistributed; all waves' pushes done

            // matvec step pk: MFMA from LDS (frozen rows' outputs are w1=0-gated)
            f32x4 acc = xi;
            #pragma unroll
            for (int ch = 0; ch < NCH; ++ch)
                acc = __builtin_amdgcn_mfma_f32_16x16x32_bf16(
                        A_s[ch*64 + lane], Breg[ch], acc, 0, 0, 0);
            // ahx accumulation (independent VALU, hides under the MFMA chain)
            #pragma unroll
            for (int j = 0; j < 6; ++j) {
                #pragma unroll
                for (int i = 0; i < 4; ++i) {
                    ahx[j*8 + i]     += w1 * bf2f((unsigned short)(clo[j] >> (16*i)));
                    ahx[j*8 + 4 + i] += w1 * bf2f((unsigned short)(chi[j] >> (16*i)));
                }
            }
            #pragma unroll
            for (int r = 0; r < 4; ++r)
                hxn_s[aq*4 + r][CT*16 + am] = f2bf(fast_tanh(acc[r] + wfl));
            __syncthreads();   // S1: hxn_s ready for next push round
            publish();
        }

        // ---- finalize t: hx_out = accum_hx / sc (all per-lane; barrier-free) ----
        const float inv = 1.f / sc;
        pc += spc;
        if (cbk == 0 && tid < RPG) out[OFF_STEPS + (size_t)t*BB + r0 + tid] = sc;
        #pragma unroll
        for (int j = 0; j < 6; ++j) {
            const int ch = j*4 + CT;
            float o[8];
            #pragma unroll
            for (int i = 0; i < 8; ++i) o[i] = ahx[j*8 + i] * inv;
            union { s16x8 v; unsigned short e[8]; } u;
            #pragma unroll
            for (int i = 0; i < 8; ++i) u.e[i] = f2bf(o[i]);
            A_s[ch*64 + lane] = u.v;   // next t's hx(k=0); guarded by next T0 barrier
            if (cbk == 0) {
                float* op = out + ((size_t)t*BB + r0 + am)*HH + ch*32 + aq*8;
                *(float4*)op       = make_float4(o[0], o[1], o[2], o[3]);
                *(float4*)(op + 4) = make_float4(o[4], o[5], o[6], o[7]);
                if (t == TT-1) {
                    float* lp = out + OFF_LAST + (size_t)(r0 + am)*HH + ch*32 + aq*8;
                    *(float4*)lp       = make_float4(o[0], o[1], o[2], o[3]);
                    *(float4*)(lp + 4) = make_float4(o[4], o[5], o[6], o[7]);
                }
            }
        }
    }
    if (cbk == 0 && tid < RPG) out[OFF_PCOST + r0 + tid] = pc;
}

extern "C" void kernel_launch(void* const* d_in, const int* in_sizes, int n_in,
                              void* d_out, int out_size, void* d_ws, size_t ws_size,
                              hipStream_t stream) {
    const float* x   = (const float*)d_in[0];
    const float* Wih = (const float*)d_in[1];
    const float* Whh = (const float*)d_in[2];
    const float* bih = (const float*)d_in[3];
    const float* bhh = (const float*)d_in[4];
    const float* wpv = (const float*)d_in[5];
    const float* bp  = (const float*)d_in[6];
    float* out = (float*)d_out;

    // ws: per-consumer push inboxes, 4-deep parity ring, sentinel-filled.
    // hx: 8 rg * 12 consumers * 4 par * 24.5KB = 9,437,184 B
    // z:  8 rg * 12 consumers * 4 par * 768 B  =   294,912 B   (total ~9.28 MB)
    const size_t hxbytes = (size_t)RG*CB*NBUF*HXW*8;
    const size_t zbytes  = (size_t)RG*CB*NBUF*ZWF*4;
    ull*   hxin = (ull*)d_ws;
    float* zin  = (float*)((char*)d_ws + hxbytes);

    hipMemsetAsync(d_ws, 0xFF, hxbytes + zbytes, stream);
    act_kernel<<<dim3(RG*CB), dim3(NTH), 0, stream>>>(
        x, Wih, Whh, bih, bhh, wpv, bp, out, hxin, zin);
}